// Round 1
// baseline (10623.715 us; speedup 1.0000x reference)
//
#include <hip/hip_runtime.h>

#define BATCH 65536
#define RT 16      // rows per block
#define RP 20      // padded row stride in LDS (float units)
#define NBLK (BATCH/RT)

// ws layout (float offsets)
#define WS_WHHT 0          // 256x1024 : W_hh transposed [k][g]
#define WS_WZT  262144     // 256x1024 : W_ih[:, :256] transposed [k][g]
#define WS_AE   524288     // 16x1024  : action_emb @ W_ih[:,384:448].T
#define WS_C4   540672     // [br][aid][1024] : bias + bid + aid contributions
#define WS_TOTAL 544768

// d_out layout (float offsets): log_p | t_actions | m_actions | t_ent | m_ent
#define OUT_LP 0
#define OUT_TA 65536
#define OUT_MA 589824
#define OUT_TENT 1114112
#define OUT_MENT 1114113

__device__ __forceinline__ float sigf(float x){ return 1.0f/(1.0f+__expf(-x)); }
__device__ __forceinline__ float tanhf_(float x){
  x = fminf(fmaxf(x, -15.0f), 15.0f);          // avoid inf/inf; tanh saturated anyway
  float e = __expf(2.0f*x);
  return (e-1.0f)/(e+1.0f);
}
__device__ __forceinline__ unsigned short f32_to_bf16(float x){
  unsigned u = __float_as_uint(x);
  unsigned r = (u + 0x7fffu + ((u>>16)&1u)) >> 16;   // RNE
  return (unsigned short)r;
}
__device__ __forceinline__ float bf16_to_f32(unsigned short h){
  return __uint_as_float(((unsigned)h)<<16);
}

__global__ void precompute_kernel(const float* __restrict__ W_ih, const float* __restrict__ W_hh,
                                  const float* __restrict__ b_ih, const float* __restrict__ b_hh,
                                  const float* __restrict__ action_emb, const float* __restrict__ branch_emb,
                                  const float* __restrict__ actionid_emb,
                                  float* __restrict__ ws, float* __restrict__ d_out) {
  int tid = blockIdx.x*256 + threadIdx.x;
  if (tid < 262144) {                       // W_hh^T : [k][g] <- W_hh[g][k]
    int k = tid >> 10, g = tid & 1023;
    ws[WS_WHHT + tid] = W_hh[g*256 + k];
  } else if (tid < 524288) {                // W_z^T : [k][g] <- W_ih[g][k], k<256
    int i = tid - 262144; int k = i >> 10, g = i & 1023;
    ws[WS_WZT + i] = W_ih[g*448 + k];
  } else if (tid < 540672) {                // AE[p][g]
    int i = tid - 524288; int p = i >> 10, g = i & 1023;
    float s = 0.f;
    for (int e = 0; e < 64; ++e) s += action_emb[p*64+e]*W_ih[g*448+384+e];
    ws[WS_AE + i] = s;
  } else if (tid < 544768) {                // C4[br][aid][g] = bias + bid + aid
    int i = tid - 540672; int cidx = i >> 10, g = i & 1023;
    int br = cidx >> 1, aid = cidx & 1;
    float s = b_ih[g] + b_hh[g];
    for (int e = 0; e < 64; ++e)
      s += branch_emb[br*64+e]*W_ih[g*448+256+e] + actionid_emb[aid*64+e]*W_ih[g*448+320+e];
    ws[WS_C4 + i] = s;
  }
  if (tid == 0) { d_out[OUT_TENT] = 0.f; d_out[OUT_MENT] = 0.f; }
}

// acc[q][r] += sum_k W[k][t+256q] * lds[k][r]   (lds reads are wave-broadcast)
__device__ __forceinline__ void gemm_acc(const float* __restrict__ Wcol, const float* lds_km, float acc[4][RT]) {
  #pragma unroll 4
  for (int k = 0; k < 256; ++k) {
    float w0 = Wcol[k*1024];
    float w1 = Wcol[k*1024+256];
    float w2 = Wcol[k*1024+512];
    float w3 = Wcol[k*1024+768];
    const float4* hp = (const float4*)(lds_km + k*RP);   // k*80B: 16B-aligned
    float4 a = hp[0], b = hp[1], cc = hp[2], d = hp[3];
    float hv[16] = {a.x,a.y,a.z,a.w, b.x,b.y,b.z,b.w, cc.x,cc.y,cc.z,cc.w, d.x,d.y,d.z,d.w};
    float wv[4] = {w0,w1,w2,w3};
    #pragma unroll
    for (int q=0;q<4;++q)
      #pragma unroll
      for (int r=0;r<RT;++r)
        acc[q][r] += wv[q]*hv[r];
  }
}

__global__ __launch_bounds__(256, 2) void decoder_main(
    const float* __restrict__ z1, const float* __restrict__ z2,
    const int* __restrict__ t_act, const int* __restrict__ m_act,
    const float* __restrict__ W_t, const float* __restrict__ b_t,
    const float* __restrict__ W_m, const float* __restrict__ b_m,
    const float* __restrict__ ws, float* __restrict__ d_out) {
  __shared__ float h_lds[256*RP];          // 20KB, [k][r]
  __shared__ float z_lds[256*RP];          // 20KB, [k][r]
  __shared__ unsigned short AE_l[16*1024]; // 32KB bf16
  __shared__ float tl_lds[RT*4];
  __shared__ float ml_lds[RT*12];
  __shared__ int prev_lds[RT];
  __shared__ int ta_lds[RT], ma_lds[RT];
  __shared__ float ent_arr[2*RT];

  const int t = threadIdx.x;               // hidden index j owned by this thread
  const int r0 = blockIdx.x * RT;
  const float* Whh = ws + WS_WHHT;
  const float* Wz  = ws + WS_WZT;
  const float* AEg = ws + WS_AE;
  const float* C4  = ws + WS_C4;

  for (int i = t; i < 16384; i += 256) AE_l[i] = f32_to_bf16(AEg[i]);
  for (int i = t; i < 256*RP; i += 256) h_lds[i] = 0.f;
  if (t < RT) prev_lds[t] = 15;            // LEN_ACT-1

  float c[RT];
  #pragma unroll
  for (int r=0;r<RT;++r) c[r]=0.f;
  float lp = 0.f, entT = 0.f, entM = 0.f;
  int mask = 0xF;

  for (int br = 0; br < 2; ++br) {
    const float* z = br ? z2 : z1;
    __syncthreads();
    #pragma unroll
    for (int r = 0; r < RT; ++r)
      z_lds[t*RP + r] = z[(r0+r)*256 + t]; // coalesced read, transposed store
    float C0[4], C1[4];
    #pragma unroll
    for (int q=0;q<4;++q) {
      C0[q] = C4[(br*2+0)*1024 + t + 256*q];
      C1[q] = C4[(br*2+1)*1024 + t + 256*q];
    }
    mask = 0xF;                            // mask resets each branch; h,c,prev persist
    __syncthreads();

    float base[4][RT];                     // z @ W_z^T, step-invariant this branch
    #pragma unroll
    for (int q=0;q<4;++q)
      #pragma unroll
      for (int r=0;r<RT;++r) base[q][r]=0.f;
    gemm_acc(Wz + t, z_lds, base);

    for (int s = 0; s < 4; ++s) {
      if (t < RT) {
        ta_lds[t] = t_act[(r0+t)*8 + br*4 + s];
        ma_lds[t] = m_act[(r0+t)*8 + br*4 + s];
      }
      __syncthreads();

      // ---- LSTM 1 (aid0, action_emb[prev]) ----
      float acc[4][RT];
      #pragma unroll
      for (int r=0;r<RT;++r) {
        int p = prev_lds[r];
        #pragma unroll
        for (int q=0;q<4;++q)
          acc[q][r] = base[q][r] + C0[q] + bf16_to_f32(AE_l[p*1024 + t + 256*q]);
      }
      gemm_acc(Whh + t, h_lds, acc);
      float hn[RT];
      #pragma unroll
      for (int r=0;r<RT;++r) {
        float gi = sigf(acc[0][r]);
        float gf = sigf(acc[1][r]);
        float gg = tanhf_(acc[2][r]);
        float go = sigf(acc[3][r]);
        float cn = gf*c[r] + gi*gg;
        c[r] = cn;
        hn[r] = go*tanhf_(cn);
      }
      __syncthreads();                     // all reads of old h done
      #pragma unroll
      for (int r=0;r<RT;++r) h_lds[t*RP + r] = hn[r];
      __syncthreads();

      // ---- t-logits (4 per row) ----
      if (t < 64) {
        int r = t >> 2, a = t & 3;
        float sacc = b_t[a];
        const float* wrow = W_t + a*256;
        for (int k=0;k<256;++k) sacc += h_lds[k*RP + r]*wrow[k];
        tl_lds[r*4+a] = sacc;
      }
      __syncthreads();
      if (t < RT) {
        int ta = ta_lds[t];
        float tl[4];
        #pragma unroll
        for (int a=0;a<4;++a) tl[a] = ((mask >> a) & 1) ? tl_lds[t*4+a] : -1e9f;
        float mx = fmaxf(fmaxf(tl[0],tl[1]),fmaxf(tl[2],tl[3]));
        float se = 0.f;
        #pragma unroll
        for (int a=0;a<4;++a) se += __expf(tl[a]-mx);
        float lse = mx + __logf(se);
        lp += tl[ta] - lse;
        float e = 0.f;
        #pragma unroll
        for (int a=0;a<4;++a) if ((mask>>a)&1) { float l2 = tl[a]-lse; e -= __expf(l2)*l2; }
        entT += e;
        mask &= ~(1<<ta);
      }

      // ---- LSTM 2 (aid1, action_emb[ta]) ----
      #pragma unroll
      for (int r=0;r<RT;++r) {
        int p = ta_lds[r];
        #pragma unroll
        for (int q=0;q<4;++q)
          acc[q][r] = base[q][r] + C1[q] + bf16_to_f32(AE_l[p*1024 + t + 256*q]);
      }
      gemm_acc(Whh + t, h_lds, acc);
      #pragma unroll
      for (int r=0;r<RT;++r) {
        float gi = sigf(acc[0][r]);
        float gf = sigf(acc[1][r]);
        float gg = tanhf_(acc[2][r]);
        float go = sigf(acc[3][r]);
        float cn = gf*c[r] + gi*gg;
        c[r] = cn;
        hn[r] = go*tanhf_(cn);
      }
      __syncthreads();
      #pragma unroll
      for (int r=0;r<RT;++r) h_lds[t*RP + r] = hn[r];
      __syncthreads();

      // ---- m-logits (11 per row) ----
      if (t < 176) {
        int r = t/11, a = t - r*11;
        float sacc = b_m[a];
        const float* wrow = W_m + a*256;
        for (int k=0;k<256;++k) sacc += h_lds[k*RP + r]*wrow[k];
        ml_lds[r*12+a] = sacc;
      }
      __syncthreads();
      if (t < RT) {
        int ma = ma_lds[t];
        float mlv[11];
        #pragma unroll
        for (int a=0;a<11;++a) mlv[a] = ml_lds[t*12+a];
        float mx = mlv[0];
        #pragma unroll
        for (int a=1;a<11;++a) mx = fmaxf(mx, mlv[a]);
        float se = 0.f;
        #pragma unroll
        for (int a=0;a<11;++a) se += __expf(mlv[a]-mx);
        float lse = mx + __logf(se);
        lp += mlv[ma] - lse;
        float e = 0.f;
        #pragma unroll
        for (int a=0;a<11;++a) { float l2 = mlv[a]-lse; e -= __expf(l2)*l2; }
        entM += e;
        prev_lds[t] = ma;                  // carry for next step / next branch
      }
      __syncthreads();
    }
  }

  // ---- outputs ----
  if (t < RT) {
    d_out[OUT_LP + r0 + t] = lp;
    ent_arr[t] = entT;
    ent_arr[RT + t] = entM;
  }
  __syncthreads();
  if (t == 0) {
    float sT=0.f, sM=0.f;
    #pragma unroll
    for (int i=0;i<RT;++i){ sT+=ent_arr[i]; sM+=ent_arr[RT+i]; }
    const float inv = 1.0f/524288.0f;      // 1/(B * 2S) , exact 2^-19
    atomicAdd(d_out + OUT_TENT, sT*inv);
    atomicAdd(d_out + OUT_MENT, sM*inv);
  }
  if (t < 128) {                           // passthrough copies, int -> float
    d_out[OUT_TA + r0*8 + t] = (float)t_act[r0*8 + t];
    d_out[OUT_MA + r0*8 + t] = (float)m_act[r0*8 + t];
  }
}

extern "C" void kernel_launch(void* const* d_in, const int* in_sizes, int n_in,
                              void* d_out, int out_size, void* d_ws, size_t ws_size,
                              hipStream_t stream) {
  const float* z1           = (const float*)d_in[0];
  const float* z2           = (const float*)d_in[1];
  const int*   t_act        = (const int*)d_in[2];
  const int*   m_act        = (const int*)d_in[3];
  const float* action_emb   = (const float*)d_in[4];
  const float* branch_emb   = (const float*)d_in[5];
  const float* actionid_emb = (const float*)d_in[6];
  const float* W_ih         = (const float*)d_in[7];
  const float* W_hh         = (const float*)d_in[8];
  const float* b_ih         = (const float*)d_in[9];
  const float* b_hh         = (const float*)d_in[10];
  const float* W_t          = (const float*)d_in[11];
  const float* b_t          = (const float*)d_in[12];
  const float* W_m          = (const float*)d_in[13];
  const float* b_m          = (const float*)d_in[14];
  float* out = (float*)d_out;
  float* ws  = (float*)d_ws;   // needs WS_TOTAL*4 = ~2.2 MB

  precompute_kernel<<<2128, 256, 0, stream>>>(W_ih, W_hh, b_ih, b_hh,
                                              action_emb, branch_emb, actionid_emb, ws, out);
  decoder_main<<<NBLK, 256, 0, stream>>>(z1, z2, t_act, m_act, W_t, b_t, W_m, b_m, ws, out);
}

// Round 2
// 10516.500 us; speedup vs baseline: 1.0102x; 1.0102x over previous
//
#include <hip/hip_runtime.h>

#define BATCH 65536
#define RT 8       // rows per block
#define RP 12      // padded row stride in LDS (float units, 48B: float4-aligned)
#define NBLK (BATCH/RT)

// ws layout (float offsets) — all weight tables packed [k][j][q] float4
#define WS_WHHT 0          // 256x256x4 : W_hh   -> [k][j][q], q = gate quadrant
#define WS_WZT  262144     // 256x256x4 : W_ih[:, :256] -> [k][j][q]
#define WS_AE   524288     // 16x256x4  : action_emb @ W_ih[:,384:448].T -> [p][j][q]
#define WS_C4   540672     // 4x256x4   : [br*2+aid][j][q] : bias + bid + aid
#define WS_TOTAL 544768

// d_out layout (float offsets): log_p | t_actions | m_actions | t_ent | m_ent
#define OUT_LP 0
#define OUT_TA 65536
#define OUT_MA 589824
#define OUT_TENT 1114112
#define OUT_MENT 1114113

__device__ __forceinline__ float sigf(float x){ return 1.0f/(1.0f+__expf(-x)); }
__device__ __forceinline__ float tanhf_(float x){
  x = fminf(fmaxf(x, -15.0f), 15.0f);
  float e = __expf(2.0f*x);
  return (e-1.0f)/(e+1.0f);
}

__global__ void precompute_kernel(const float* __restrict__ W_ih, const float* __restrict__ W_hh,
                                  const float* __restrict__ b_ih, const float* __restrict__ b_hh,
                                  const float* __restrict__ action_emb, const float* __restrict__ branch_emb,
                                  const float* __restrict__ actionid_emb,
                                  float* __restrict__ ws, float* __restrict__ d_out) {
  int tid = blockIdx.x*256 + threadIdx.x;
  if (tid < 262144) {                       // W_hh -> [k][j][q]
    int q = tid & 3, j = (tid >> 2) & 255, k = tid >> 10;
    ws[WS_WHHT + tid] = W_hh[(j + 256*q)*256 + k];
  } else if (tid < 524288) {                // W_ih[:, :256] -> [k][j][q]
    int i = tid - 262144;
    int q = i & 3, j = (i >> 2) & 255, k = i >> 10;
    ws[WS_WZT + i] = W_ih[(j + 256*q)*448 + k];
  } else if (tid < 540672) {                // AE[p][j][q]
    int i = tid - 524288;
    int q = i & 3, j = (i >> 2) & 255, p = i >> 10;
    int g = j + 256*q;
    float s = 0.f;
    for (int e = 0; e < 64; ++e) s += action_emb[p*64+e]*W_ih[g*448+384+e];
    ws[WS_AE + i] = s;
  } else if (tid < 544768) {                // C4[br*2+aid][j][q]
    int i = tid - 540672;
    int q = i & 3, j = (i >> 2) & 255, cidx = i >> 10;
    int g = j + 256*q;
    int br = cidx >> 1, aid = cidx & 1;
    float s = b_ih[g] + b_hh[g];
    for (int e = 0; e < 64; ++e)
      s += branch_emb[br*64+e]*W_ih[g*448+256+e] + actionid_emb[aid*64+e]*W_ih[g*448+320+e];
    ws[WS_C4 + i] = s;
  }
  if (tid == 0) { d_out[OUT_TENT] = 0.f; d_out[OUT_MENT] = 0.f; }
}

// acc[q][r] += sum_k W4[k*1024 + 4q..] * lds[k][r]; W4 pre-offset by t*4.
// LDS reads are wave-uniform (broadcast, conflict-free); weight read is one dwordx4/lane.
__device__ __forceinline__ void gemm_acc(const float* __restrict__ W4, const float* lds_km, float acc[4][RT]) {
  #pragma unroll 4
  for (int k = 0; k < 256; ++k) {
    const float4 w = *(const float4*)(W4 + k*1024);
    const float4* hp = (const float4*)(lds_km + k*RP);
    float4 a = hp[0], b = hp[1];
    float hv[8] = {a.x,a.y,a.z,a.w, b.x,b.y,b.z,b.w};
    #pragma unroll
    for (int r = 0; r < RT; ++r) {
      acc[0][r] += w.x*hv[r];
      acc[1][r] += w.y*hv[r];
      acc[2][r] += w.z*hv[r];
      acc[3][r] += w.w*hv[r];
    }
  }
}

__global__ __launch_bounds__(256, 2) void decoder_main(
    const float* __restrict__ z1, const float* __restrict__ z2,
    const int* __restrict__ t_act, const int* __restrict__ m_act,
    const float* __restrict__ W_t, const float* __restrict__ b_t,
    const float* __restrict__ W_m, const float* __restrict__ b_m,
    const float* __restrict__ ws, float* __restrict__ d_out) {
  __shared__ float h_lds[256*RP];          // 12KB, [k][r]
  __shared__ float z_lds[256*RP];          // 12KB, [k][r]
  __shared__ float tl_lds[RT*4];
  __shared__ float ml_lds[RT*12];
  __shared__ int prev_lds[RT];
  __shared__ int ta_lds[RT], ma_lds[RT];
  __shared__ float ent_arr[2*RT];

  const int t = threadIdx.x;               // hidden index j owned by this thread
  const int r0 = blockIdx.x * RT;
  const float* Whh4 = ws + WS_WHHT + t*4;
  const float* Wz4  = ws + WS_WZT + t*4;
  const float* AEg  = ws + WS_AE;
  const float* C4   = ws + WS_C4;

  for (int i = t; i < 256*RP; i += 256) h_lds[i] = 0.f;
  if (t < RT) prev_lds[t] = 15;            // LEN_ACT-1

  float c[RT];
  #pragma unroll
  for (int r=0;r<RT;++r) c[r]=0.f;
  float lp = 0.f, entT = 0.f, entM = 0.f;
  int mask = 0xF;

  for (int br = 0; br < 2; ++br) {
    const float* z = br ? z2 : z1;
    __syncthreads();
    #pragma unroll
    for (int r = 0; r < RT; ++r)
      z_lds[t*RP + r] = z[(r0+r)*256 + t]; // coalesced read, transposed store
    const float4 C0 = *(const float4*)(C4 + (br*2+0)*1024 + t*4);
    const float4 C1 = *(const float4*)(C4 + (br*2+1)*1024 + t*4);
    mask = 0xF;                            // mask resets each branch; h,c,prev persist
    __syncthreads();

    float base[4][RT];                     // z @ W_z^T, step-invariant this branch
    #pragma unroll
    for (int q=0;q<4;++q)
      #pragma unroll
      for (int r=0;r<RT;++r) base[q][r]=0.f;
    gemm_acc(Wz4, z_lds, base);

    for (int s = 0; s < 4; ++s) {
      if (t < RT) {
        ta_lds[t] = t_act[(r0+t)*8 + br*4 + s];
        ma_lds[t] = m_act[(r0+t)*8 + br*4 + s];
      }
      __syncthreads();

      // ---- LSTM 1 (aid0, action_emb[prev]) ----
      float acc[4][RT];
      #pragma unroll
      for (int r=0;r<RT;++r) {
        int p = prev_lds[r];
        const float4 ae = *(const float4*)(AEg + p*1024 + t*4);  // L2-resident, coalesced
        acc[0][r] = base[0][r] + C0.x + ae.x;
        acc[1][r] = base[1][r] + C0.y + ae.y;
        acc[2][r] = base[2][r] + C0.z + ae.z;
        acc[3][r] = base[3][r] + C0.w + ae.w;
      }
      gemm_acc(Whh4, h_lds, acc);
      float hn[RT];
      #pragma unroll
      for (int r=0;r<RT;++r) {
        float gi = sigf(acc[0][r]);
        float gf = sigf(acc[1][r]);
        float gg = tanhf_(acc[2][r]);
        float go = sigf(acc[3][r]);
        float cn = gf*c[r] + gi*gg;
        c[r] = cn;
        hn[r] = go*tanhf_(cn);
      }
      __syncthreads();                     // all reads of old h done
      #pragma unroll
      for (int r=0;r<RT;++r) h_lds[t*RP + r] = hn[r];
      __syncthreads();

      // ---- t-logits (4 per row) ----
      if (t < RT*4) {
        int r = t >> 2, a = t & 3;
        float sacc = b_t[a];
        const float* wrow = W_t + a*256;
        for (int k=0;k<256;++k) sacc += h_lds[k*RP + r]*wrow[k];
        tl_lds[r*4+a] = sacc;
      }
      __syncthreads();
      if (t < RT) {
        int ta = ta_lds[t];
        float tl[4];
        #pragma unroll
        for (int a=0;a<4;++a) tl[a] = ((mask >> a) & 1) ? tl_lds[t*4+a] : -1e9f;
        float mx = fmaxf(fmaxf(tl[0],tl[1]),fmaxf(tl[2],tl[3]));
        float se = 0.f;
        #pragma unroll
        for (int a=0;a<4;++a) se += __expf(tl[a]-mx);
        float lse = mx + __logf(se);
        lp += tl[ta] - lse;
        float e = 0.f;
        #pragma unroll
        for (int a=0;a<4;++a) if ((mask>>a)&1) { float l2 = tl[a]-lse; e -= __expf(l2)*l2; }
        entT += e;
        mask &= ~(1<<ta);
      }

      // ---- LSTM 2 (aid1, action_emb[ta]) ----
      #pragma unroll
      for (int r=0;r<RT;++r) {
        int p = ta_lds[r];
        const float4 ae = *(const float4*)(AEg + p*1024 + t*4);
        acc[0][r] = base[0][r] + C1.x + ae.x;
        acc[1][r] = base[1][r] + C1.y + ae.y;
        acc[2][r] = base[2][r] + C1.z + ae.z;
        acc[3][r] = base[3][r] + C1.w + ae.w;
      }
      gemm_acc(Whh4, h_lds, acc);
      #pragma unroll
      for (int r=0;r<RT;++r) {
        float gi = sigf(acc[0][r]);
        float gf = sigf(acc[1][r]);
        float gg = tanhf_(acc[2][r]);
        float go = sigf(acc[3][r]);
        float cn = gf*c[r] + gi*gg;
        c[r] = cn;
        hn[r] = go*tanhf_(cn);
      }
      __syncthreads();
      #pragma unroll
      for (int r=0;r<RT;++r) h_lds[t*RP + r] = hn[r];
      __syncthreads();

      // ---- m-logits (11 per row) ----
      if (t < RT*11) {
        int r = t/11, a = t - r*11;
        float sacc = b_m[a];
        const float* wrow = W_m + a*256;
        for (int k=0;k<256;++k) sacc += h_lds[k*RP + r]*wrow[k];
        ml_lds[r*12+a] = sacc;
      }
      __syncthreads();
      if (t < RT) {
        int ma = ma_lds[t];
        float mlv[11];
        #pragma unroll
        for (int a=0;a<11;++a) mlv[a] = ml_lds[t*12+a];
        float mx = mlv[0];
        #pragma unroll
        for (int a=1;a<11;++a) mx = fmaxf(mx, mlv[a]);
        float se = 0.f;
        #pragma unroll
        for (int a=0;a<11;++a) se += __expf(mlv[a]-mx);
        float lse = mx + __logf(se);
        lp += mlv[ma] - lse;
        float e = 0.f;
        #pragma unroll
        for (int a=0;a<11;++a) { float l2 = mlv[a]-lse; e -= __expf(l2)*l2; }
        entM += e;
        prev_lds[t] = ma;                  // carry for next step / next branch
      }
      __syncthreads();
    }
  }

  // ---- outputs ----
  if (t < RT) {
    d_out[OUT_LP + r0 + t] = lp;
    ent_arr[t] = entT;
    ent_arr[RT + t] = entM;
  }
  __syncthreads();
  if (t == 0) {
    float sT=0.f, sM=0.f;
    #pragma unroll
    for (int i=0;i<2*RT;++i){ if (i<RT) sT+=ent_arr[i]; else sM+=ent_arr[i]; }
    const float inv = 1.0f/524288.0f;      // 1/(B * 2S), exact 2^-19
    atomicAdd(d_out + OUT_TENT, sT*inv);
    atomicAdd(d_out + OUT_MENT, sM*inv);
  }
  if (t < RT*8) {                          // passthrough copies, int -> float
    d_out[OUT_TA + r0*8 + t] = (float)t_act[r0*8 + t];
    d_out[OUT_MA + r0*8 + t] = (float)m_act[r0*8 + t];
  }
}

extern "C" void kernel_launch(void* const* d_in, const int* in_sizes, int n_in,
                              void* d_out, int out_size, void* d_ws, size_t ws_size,
                              hipStream_t stream) {
  const float* z1           = (const float*)d_in[0];
  const float* z2           = (const float*)d_in[1];
  const int*   t_act        = (const int*)d_in[2];
  const int*   m_act        = (const int*)d_in[3];
  const float* action_emb   = (const float*)d_in[4];
  const float* branch_emb   = (const float*)d_in[5];
  const float* actionid_emb = (const float*)d_in[6];
  const float* W_ih         = (const float*)d_in[7];
  const float* W_hh         = (const float*)d_in[8];
  const float* b_ih         = (const float*)d_in[9];
  const float* b_hh         = (const float*)d_in[10];
  const float* W_t          = (const float*)d_in[11];
  const float* b_t          = (const float*)d_in[12];
  const float* W_m          = (const float*)d_in[13];
  const float* b_m          = (const float*)d_in[14];
  float* out = (float*)d_out;
  float* ws  = (float*)d_ws;   // needs WS_TOTAL*4 = ~2.2 MB

  precompute_kernel<<<2128, 256, 0, stream>>>(W_ih, W_hh, b_ih, b_hh,
                                              action_emb, branch_emb, actionid_emb, ws, out);
  decoder_main<<<NBLK, 256, 0, stream>>>(z1, z2, t_act, m_act, W_t, b_t, W_m, b_m, ws, out);
}

// Round 3
// 7468.008 us; speedup vs baseline: 1.4226x; 1.4082x over previous
//
#include <hip/hip_runtime.h>

#define BATCH 65536
#define RT 32              // rows per block
#define NBLK (BATCH/RT)    // 2048
#define HS 264             // bf16 elems per LDS row (256 + 8 pad; 528B, 16B-aligned)

typedef __bf16 v8bf __attribute__((ext_vector_type(8)));
typedef float  v4f  __attribute__((ext_vector_type(4)));
#define MFMA __builtin_amdgcn_mfma_f32_16x16x32_bf16

// ws layout, bf16-element offsets
#define WHH_ELE 0          // 8kc x 4w x 16nt x 64lane x 8j   (512KB)
#define WZ_ELE  262144     // same shape, W_ih[:, :256]       (512KB)
#define EXT_ELE 524288     // 4w x 16nt x 64lane x 8j : one-hot table (64KB)
#define WT_ELE  557056     // 8kc x 64lane x 8j : W_t padded N=16 (8KB)
#define WM_ELE  561152     // 8kc x 64lane x 8j : W_m padded N=16 (8KB)
#define WS_ELE_TOTAL 565248

// d_out layout (float offsets): log_p | t_actions | m_actions | t_ent | m_ent
#define OUT_LP 0
#define OUT_TA 65536
#define OUT_MA 589824
#define OUT_TENT 1114112
#define OUT_MENT 1114113

__device__ __forceinline__ float sigf(float x){ return 1.0f/(1.0f+__expf(-x)); }
__device__ __forceinline__ float tanhf_(float x){
  x = fminf(fmaxf(x, -15.0f), 15.0f);
  float e = __expf(2.0f*x);
  return (e-1.0f)/(e+1.0f);
}
__device__ __forceinline__ unsigned short f32_to_bf16(float x){
  unsigned u = __float_as_uint(x);
  unsigned r = (u + 0x7fffu + ((u>>16)&1u)) >> 16;   // RNE
  return (unsigned short)r;
}

// gate-column permutation: wave w, ntile nt, col -> original gate row g
// g = (nt>>2)*256 + w*64 + (nt&3)*16 + col   (gate = nt>>2, unit = w*64+(nt&3)*16+col)
__global__ void precompute_kernel(const float* __restrict__ W_ih, const float* __restrict__ W_hh,
                                  const float* __restrict__ b_ih, const float* __restrict__ b_hh,
                                  const float* __restrict__ action_emb, const float* __restrict__ branch_emb,
                                  const float* __restrict__ actionid_emb,
                                  const float* __restrict__ W_t, const float* __restrict__ W_m,
                                  unsigned short* __restrict__ wsp, float* __restrict__ d_out) {
  int tid = blockIdx.x*256 + threadIdx.x;
  if (tid == 0) { d_out[OUT_TENT] = 0.f; d_out[OUT_MENT] = 0.f; }
  if (tid >= WS_ELE_TOTAL) return;
  float val = 0.f;
  if (tid < 524288) {                        // WHH / WZ packs
    int i = (tid < 262144) ? tid : tid - 262144;
    int j = i & 7, lane = (i>>3)&63, nt = (i>>9)&15, w = (i>>13)&3, kc = (i>>15)&7;
    int k = kc*32 + (lane>>4)*8 + j;
    int g = (nt>>2)*256 + w*64 + (nt&3)*16 + (lane&15);
    val = (tid < 262144) ? W_hh[g*256 + k] : W_ih[g*448 + k];
  } else if (tid < 557056) {                 // EXT: one-hot table, K=32
    int i = tid - 524288;
    int j = i & 7, lane = (i>>3)&63, nt = (i>>9)&15, w = (i>>13)&3;
    int p = (lane>>4)*8 + j;                 // K index = table row
    int g = (nt>>2)*256 + w*64 + (nt&3)*16 + (lane&15);
    if (p < 16) {                            // AE[p][g]
      float s = 0.f;
      for (int e=0;e<64;++e) s += action_emb[p*64+e]*W_ih[g*448+384+e];
      val = s;
    } else if (p < 20) {                     // bias + bid + aid
      int q = p-16, br = q>>1, aid = q&1;
      float s = b_ih[g] + b_hh[g];
      for (int e=0;e<64;++e)
        s += branch_emb[br*64+e]*W_ih[g*448+256+e] + actionid_emb[aid*64+e]*W_ih[g*448+320+e];
      val = s;
    }
  } else {                                   // WT / WM packs (N padded to 16)
    int base = (tid < 561152) ? 557056 : 561152;
    int i = tid - base;
    int j = i & 7, lane = (i>>3)&63, kc = (i>>9)&7;
    int k = kc*32 + (lane>>4)*8 + j;
    int a = lane & 15;
    if (tid < 561152) val = (a < 4)  ? W_t[a*256 + k] : 0.f;
    else              val = (a < 11) ? W_m[a*256 + k] : 0.f;
  }
  wsp[tid] = f32_to_bf16(val);
}

// acc[mt][nt] += A(hbase rows) * Bpack  over K=256 (8 chunks)
__device__ __forceinline__ void run_gemm(v4f acc[2][16], const v8bf* __restrict__ Bw,
                                         const unsigned short* hbase, int col, int quad) {
  #pragma unroll
  for (int kc = 0; kc < 8; ++kc) {
    v8bf A0 = *(const v8bf*)&hbase[(col   )*HS + kc*32 + quad*8];
    v8bf A1 = *(const v8bf*)&hbase[(16+col)*HS + kc*32 + quad*8];
    #pragma unroll
    for (int nt = 0; nt < 16; ++nt) {
      v8bf B = Bw[kc*4096 + nt*64];
      acc[0][nt] = MFMA(A0, B, acc[0][nt], 0,0,0);
      acc[1][nt] = MFMA(A1, B, acc[1][nt], 0,0,0);
    }
  }
}

// one-hot K=32 chunk: adds T[idx[row]] + T[cidx] to each row's gates
__device__ __forceinline__ void run_ext(v4f acc[2][16], const v8bf* __restrict__ Ew,
                                        const int* idx_lds, int cidx, int col, int quad) {
  v8bf oh0, oh1;
  int p0 = idx_lds[col], p1 = idx_lds[16+col];
  #pragma unroll
  for (int j=0;j<8;++j) {
    int k = quad*8+j;
    oh0[j] = (k==p0 || k==cidx) ? (__bf16)1.0f : (__bf16)0.0f;
    oh1[j] = (k==p1 || k==cidx) ? (__bf16)1.0f : (__bf16)0.0f;
  }
  #pragma unroll
  for (int nt=0; nt<16; ++nt) {
    v8bf B = Ew[nt*64];
    acc[0][nt] = MFMA(oh0, B, acc[0][nt], 0,0,0);
    acc[1][nt] = MFMA(oh1, B, acc[1][nt], 0,0,0);
  }
}

__global__ __launch_bounds__(256, 1) void decoder_main(
    const float* __restrict__ z1, const float* __restrict__ z2,
    const int* __restrict__ t_act, const int* __restrict__ m_act,
    const float* __restrict__ b_t, const float* __restrict__ b_m,
    const unsigned short* __restrict__ wsp, float* __restrict__ d_out) {
  __shared__ __align__(16) unsigned short h_lds[RT*HS];   // 16.9KB, [row][k] bf16
  __shared__ __align__(16) unsigned short z_lds[RT*HS];   // 16.9KB
  __shared__ float tl_lds[RT*4];
  __shared__ float ml_lds[RT*12];
  __shared__ int prev_lds[RT], ta_lds[RT], ma_lds[RT];
  __shared__ float ent_arr[2*RT];

  const int t = threadIdx.x, w = t>>6, l = t&63, col = l&15, quad = l>>4;
  const int r0 = blockIdx.x * RT;
  const v8bf* Bhh = ((const v8bf*)(wsp + WHH_ELE)) + w*1024 + l;
  const v8bf* Bz  = ((const v8bf*)(wsp + WZ_ELE))  + w*1024 + l;
  const v8bf* Ew  = ((const v8bf*)(wsp + EXT_ELE)) + w*1024 + l;
  const v8bf* Wtp = ((const v8bf*)(wsp + WT_ELE))  + l;
  const v8bf* Wmp = ((const v8bf*)(wsp + WM_ELE))  + l;

  for (int i = t; i < RT*HS; i += 256) h_lds[i] = 0;
  if (t < RT) prev_lds[t] = 15;            // LEN_ACT-1

  float c_st[2][4][4];
  #pragma unroll
  for (int mt=0;mt<2;++mt)
    #pragma unroll
    for (int n=0;n<4;++n)
      #pragma unroll
      for (int rg=0;rg<4;++rg) c_st[mt][n][rg]=0.f;
  float lp = 0.f, entT = 0.f, entM = 0.f;
  int mask = 0xF;

  for (int br = 0; br < 2; ++br) {
    const float* z = br ? z2 : z1;
    // stage z -> LDS bf16, A-layout [row][k]
    #pragma unroll
    for (int it = 0; it < 4; ++it) {
      int r = (t>>5) + it*8, c0 = (t&31)*8;
      const float4 f0 = *(const float4*)&z[(r0+r)*256 + c0];
      const float4 f1 = *(const float4*)&z[(r0+r)*256 + c0 + 4];
      uint4 pk;
      pk.x = (unsigned)f32_to_bf16(f0.x) | ((unsigned)f32_to_bf16(f0.y)<<16);
      pk.y = (unsigned)f32_to_bf16(f0.z) | ((unsigned)f32_to_bf16(f0.w)<<16);
      pk.z = (unsigned)f32_to_bf16(f1.x) | ((unsigned)f32_to_bf16(f1.y)<<16);
      pk.w = (unsigned)f32_to_bf16(f1.z) | ((unsigned)f32_to_bf16(f1.w)<<16);
      *(uint4*)&z_lds[r*HS + c0] = pk;
    }
    mask = 0xF;
    __syncthreads();

    // base = z @ Wz^T (fp32, stays in registers as acc initializer)
    v4f base[2][16];
    #pragma unroll
    for (int mt=0;mt<2;++mt)
      #pragma unroll
      for (int nt=0;nt<16;++nt) base[mt][nt] = (v4f){0.f,0.f,0.f,0.f};
    run_gemm(base, Bz, z_lds, col, quad);

    for (int s = 0; s < 4; ++s) {
      if (t < RT) {
        ta_lds[t] = t_act[(r0+t)*8 + br*4 + s];
        ma_lds[t] = m_act[(r0+t)*8 + br*4 + s];
      }
      __syncthreads();                                   // (1) ta/ma/prev visible

      // ---- LSTM 1 : gates = base + h@Whh^T + onehot(prev, C[br][0]) ----
      v4f acc[2][16];
      #pragma unroll
      for (int mt=0;mt<2;++mt)
        #pragma unroll
        for (int nt=0;nt<16;++nt) acc[mt][nt] = base[mt][nt];
      run_gemm(acc, Bhh, h_lds, col, quad);
      run_ext(acc, Ew, prev_lds, 16 + 2*br + 0, col, quad);
      float hv[2][4][4];
      #pragma unroll
      for (int mt=0;mt<2;++mt)
        #pragma unroll
        for (int n=0;n<4;++n)
          #pragma unroll
          for (int rg=0;rg<4;++rg) {
            float gi = sigf(acc[mt][n][rg]);
            float gf = sigf(acc[mt][n+4][rg]);
            float gg = tanhf_(acc[mt][n+8][rg]);
            float go = sigf(acc[mt][n+12][rg]);
            float cn = gf*c_st[mt][n][rg] + gi*gg;
            c_st[mt][n][rg] = cn;
            hv[mt][n][rg] = go*tanhf_(cn);
          }
      __syncthreads();                                   // (2) all h reads done
      #pragma unroll
      for (int mt=0;mt<2;++mt)
        #pragma unroll
        for (int n=0;n<4;++n)
          #pragma unroll
          for (int rg=0;rg<4;++rg)
            h_lds[(mt*16 + quad*4 + rg)*HS + w*64 + n*16 + col] = f32_to_bf16(hv[mt][n][rg]);
      __syncthreads();                                   // (3) new h visible

      // ---- t-logits via MFMA (waves 0,1; N padded to 16, 4 valid) ----
      if (w < 2) {
        v4f lacc = (v4f){0.f,0.f,0.f,0.f};
        #pragma unroll
        for (int kc=0;kc<8;++kc) {
          v8bf A = *(const v8bf*)&h_lds[(w*16+col)*HS + kc*32 + quad*8];
          lacc = MFMA(A, Wtp[kc*64], lacc, 0,0,0);
        }
        if (col < 4) {
          #pragma unroll
          for (int rg=0;rg<4;++rg) tl_lds[(w*16 + quad*4 + rg)*4 + col] = lacc[rg];
        }
      }
      __syncthreads();                                   // (4) logits visible
      if (t < RT) {
        int ta = ta_lds[t];
        float tl[4];
        #pragma unroll
        for (int a=0;a<4;++a) {
          float raw = tl_lds[t*4+a] + b_t[a];
          tl[a] = ((mask>>a)&1) ? raw : -1e9f;
        }
        float mx = fmaxf(fmaxf(tl[0],tl[1]),fmaxf(tl[2],tl[3]));
        float se = 0.f;
        #pragma unroll
        for (int a=0;a<4;++a) se += __expf(tl[a]-mx);
        float lse = mx + __logf(se);
        lp += tl[ta] - lse;
        float e = 0.f;
        #pragma unroll
        for (int a=0;a<4;++a) if ((mask>>a)&1) { float l2 = tl[a]-lse; e -= __expf(l2)*l2; }
        entT += e;
        mask &= ~(1<<ta);
      }

      // ---- LSTM 2 : gates = base + h@Whh^T + onehot(ta, C[br][1]) ----
      #pragma unroll
      for (int mt=0;mt<2;++mt)
        #pragma unroll
        for (int nt=0;nt<16;++nt) acc[mt][nt] = base[mt][nt];
      run_gemm(acc, Bhh, h_lds, col, quad);
      run_ext(acc, Ew, ta_lds, 16 + 2*br + 1, col, quad);
      #pragma unroll
      for (int mt=0;mt<2;++mt)
        #pragma unroll
        for (int n=0;n<4;++n)
          #pragma unroll
          for (int rg=0;rg<4;++rg) {
            float gi = sigf(acc[mt][n][rg]);
            float gf = sigf(acc[mt][n+4][rg]);
            float gg = tanhf_(acc[mt][n+8][rg]);
            float go = sigf(acc[mt][n+12][rg]);
            float cn = gf*c_st[mt][n][rg] + gi*gg;
            c_st[mt][n][rg] = cn;
            hv[mt][n][rg] = go*tanhf_(cn);
          }
      __syncthreads();                                   // (5)
      #pragma unroll
      for (int mt=0;mt<2;++mt)
        #pragma unroll
        for (int n=0;n<4;++n)
          #pragma unroll
          for (int rg=0;rg<4;++rg)
            h_lds[(mt*16 + quad*4 + rg)*HS + w*64 + n*16 + col] = f32_to_bf16(hv[mt][n][rg]);
      __syncthreads();                                   // (6)

      // ---- m-logits via MFMA (waves 0,1; 11 valid) ----
      if (w < 2) {
        v4f lacc = (v4f){0.f,0.f,0.f,0.f};
        #pragma unroll
        for (int kc=0;kc<8;++kc) {
          v8bf A = *(const v8bf*)&h_lds[(w*16+col)*HS + kc*32 + quad*8];
          lacc = MFMA(A, Wmp[kc*64], lacc, 0,0,0);
        }
        if (col < 11) {
          #pragma unroll
          for (int rg=0;rg<4;++rg) ml_lds[(w*16 + quad*4 + rg)*12 + col] = lacc[rg];
        }
      }
      __syncthreads();                                   // (7)
      if (t < RT) {
        int ma = ma_lds[t];
        float mlv[11];
        #pragma unroll
        for (int a=0;a<11;++a) mlv[a] = ml_lds[t*12+a] + b_m[a];
        float mx = mlv[0];
        #pragma unroll
        for (int a=1;a<11;++a) mx = fmaxf(mx, mlv[a]);
        float se = 0.f;
        #pragma unroll
        for (int a=0;a<11;++a) se += __expf(mlv[a]-mx);
        float lse = mx + __logf(se);
        lp += mlv[ma] - lse;
        float e = 0.f;
        #pragma unroll
        for (int a=0;a<11;++a) { float l2 = mlv[a]-lse; e -= __expf(l2)*l2; }
        entM += e;
        prev_lds[t] = ma;                                // carry (synced by next (1))
      }
    }
  }

  // ---- outputs ----
  if (t < RT) {
    d_out[OUT_LP + r0 + t] = lp;
    ent_arr[t] = entT;
    ent_arr[RT + t] = entM;
  }
  __syncthreads();
  if (t == 0) {
    float sT=0.f, sM=0.f;
    for (int i=0;i<RT;++i){ sT+=ent_arr[i]; sM+=ent_arr[RT+i]; }
    const float inv = 1.0f/524288.0f;                    // 1/(B*2S), exact 2^-19
    atomicAdd(d_out + OUT_TENT, sT*inv);
    atomicAdd(d_out + OUT_MENT, sM*inv);
  }
  // passthrough copies: RT*8 = 256 elements each
  d_out[OUT_TA + r0*8 + t] = (float)t_act[r0*8 + t];
  d_out[OUT_MA + r0*8 + t] = (float)m_act[r0*8 + t];
}

extern "C" void kernel_launch(void* const* d_in, const int* in_sizes, int n_in,
                              void* d_out, int out_size, void* d_ws, size_t ws_size,
                              hipStream_t stream) {
  const float* z1           = (const float*)d_in[0];
  const float* z2           = (const float*)d_in[1];
  const int*   t_act        = (const int*)d_in[2];
  const int*   m_act        = (const int*)d_in[3];
  const float* action_emb   = (const float*)d_in[4];
  const float* branch_emb   = (const float*)d_in[5];
  const float* actionid_emb = (const float*)d_in[6];
  const float* W_ih         = (const float*)d_in[7];
  const float* W_hh         = (const float*)d_in[8];
  const float* b_ih         = (const float*)d_in[9];
  const float* b_hh         = (const float*)d_in[10];
  const float* W_t          = (const float*)d_in[11];
  const float* b_t          = (const float*)d_in[12];
  const float* W_m          = (const float*)d_in[13];
  const float* b_m          = (const float*)d_in[14];
  float* out = (float*)d_out;
  unsigned short* wsp = (unsigned short*)d_ws;   // 565248 bf16 = 1.13MB

  precompute_kernel<<<(WS_ELE_TOTAL+255)/256, 256, 0, stream>>>(
      W_ih, W_hh, b_ih, b_hh, action_emb, branch_emb, actionid_emb, W_t, W_m, wsp, out);
  decoder_main<<<NBLK, 256, 0, stream>>>(z1, z2, t_act, m_act, b_t, b_m, wsp, out);
}